// Round 1
// baseline (321.530 us; speedup 1.0000x reference)
//
#include <hip/hip_runtime.h>

// IIR filterbank: x (128, 4, 65536) f32, DF2T order-4 per (batch, filter).
// Poles all at radius 0.9 (a4 = 0.9^4) -> 512-sample zero-state warmup is
// exact to float precision (0.9^512 ~ 4e-24). Overlap-save chunking:
// 512 seqs x 128 chunks of 512 = 65536 independent threads.

#define SEQ_LEN 65536
#define CHUNK   512
#define WARM    512
#define NCHUNKS 128            // per sequence = SEQ_LEN / CHUNK
#define NSEQ    512            // 128 batch * 4 filters
#define BLOCK   256

__global__ __launch_bounds__(BLOCK) void iir_chunk_kernel(
    const float* __restrict__ x,
    const float* __restrict__ bc,
    const float* __restrict__ ac,
    float* __restrict__ out)
{
    const int tid = blockIdx.x * BLOCK + threadIdx.x;   // one thread per chunk
    const int seq = tid >> 7;          // tid / NCHUNKS
    const int cin = tid & 127;         // chunk index within sequence
    const int f   = seq & 3;           // filter id (seq = batch*4 + f)

    const float a0i = 1.0f / ac[f * 5 + 0];
    const float b0 = bc[f * 5 + 0] * a0i;
    const float b1 = bc[f * 5 + 1] * a0i;
    const float b2 = bc[f * 5 + 2] * a0i;
    const float b3 = bc[f * 5 + 3] * a0i;
    const float b4 = bc[f * 5 + 4] * a0i;
    const float a1 = ac[f * 5 + 1] * a0i;
    const float a2 = ac[f * 5 + 2] * a0i;
    const float a3 = ac[f * 5 + 3] * a0i;
    const float a4 = ac[f * 5 + 4] * a0i;

    const long long base = (long long)seq * SEQ_LEN + (long long)cin * CHUNK;
    const int wlen  = (cin == 0) ? 0 : WARM;           // chunk 0: z0 = 0 exact
    const int skip4 = wlen >> 2;                       // 0 or 128
    const int n4    = (wlen + CHUNK) >> 2;             // 128 or 256

    const float4* __restrict__ xs = reinterpret_cast<const float4*>(x + base - wlen);
    float4* __restrict__ os       = reinterpret_cast<float4*>(out + base - wlen);

    float z1 = 0.f, z2 = 0.f, z3 = 0.f, z4 = 0.f;

    auto step = [&](float xv) -> float {
        float y = fmaf(b0, xv, z1);
        z1 = fmaf(-a1, y, fmaf(b1, xv, z2));
        z2 = fmaf(-a2, y, fmaf(b2, xv, z3));
        z3 = fmaf(-a3, y, fmaf(b3, xv, z4));
        z4 = fmaf(-a4, y, b4 * xv);
        return y;
    };

    // Depth-3 rotating prefetch; (i+3)&255 wraps to already-hot lines at the
    // tail (L1 hits, branch-free). cin==0 lanes read xs[0..255] = their own
    // 1024 in-bounds floats; only i<n4 results are stored.
    float4 p0 = xs[0], p1 = xs[1], p2 = xs[2];
    #pragma unroll 4
    for (int i = 0; i < 256; ++i) {
        float4 v = p0;
        p0 = p1; p1 = p2;
        p2 = xs[(i + 3) & 255];
        float4 o;
        o.x = step(v.x);
        o.y = step(v.y);
        o.z = step(v.z);
        o.w = step(v.w);
        if (i >= skip4 && i < n4) os[i] = o;
    }
}

extern "C" void kernel_launch(void* const* d_in, const int* in_sizes, int n_in,
                              void* d_out, int out_size, void* d_ws, size_t ws_size,
                              hipStream_t stream) {
    const float* x = (const float*)d_in[0];
    const float* b = (const float*)d_in[1];
    const float* a = (const float*)d_in[2];
    float* out = (float*)d_out;

    const int total_threads = NSEQ * NCHUNKS;          // 65536
    iir_chunk_kernel<<<dim3(total_threads / BLOCK), dim3(BLOCK), 0, stream>>>(
        x, b, a, out);
}